// Round 3
// 185.234 us; speedup vs baseline: 1.0036x; 1.0036x over previous
//
#include <hip/hip_runtime.h>

#define BATCH 4096
#define DIM 4096
#define NSPLIT 64
#define ROWS_PB 128
#define NCHUNK 32            // BATCH / ROWS_PB
#define BN_EPS 1e-3f

typedef __attribute__((ext_vector_type(8))) short bf16x8;
typedef __attribute__((ext_vector_type(4))) float f32x4;

__device__ inline unsigned short f2bf(float f) {
    union { float f; unsigned int u; } c; c.f = f;
    unsigned int u = c.u;
    u += 0x7FFFu + ((u >> 16) & 1u);   // round-to-nearest-even
    return (unsigned short)(u >> 16);
}

// K1: GEMM once. Emits per-block column sum/sumsq partials into part (1 MiB
// workspace — same footprint the baseline validated) and the pre-BN fp32
// activations straight into out at their final addresses.
// Bias is dropped: it cancels exactly under BatchNorm mean-subtraction
// ((y+b)-mean(y+b) == y-mean(y), var unchanged).
__global__ __launch_bounds__(256) void gemm_stats(
    const float* __restrict__ x, const float* __restrict__ w,
    float* __restrict__ part, float* __restrict__ out)
{
    __shared__ unsigned short xs[ROWS_PB][72];   // +8 pad: 2-way aliasing only (free)
    __shared__ unsigned short wt[64][72];
    __shared__ float red1[4][64], red2[4][64];

    const int s  = blockIdx.y;
    const int r0 = blockIdx.x * ROWS_PB;
    const int t  = threadIdx.x;
    const int lane = t & 63, wave = t >> 6;
    const int quad = lane >> 4, l16 = lane & 15;

    // stage W_s transposed (fp32 -> bf16), coalesced float4 reads
    for (int i = t; i < 1024; i += 256) {
        int k = i >> 4, c4 = i & 15;
        float4 v = *(const float4*)(w + (size_t)(s*64 + k) * DIM + s*64 + c4*4);
        wt[c4*4 + 0][k] = f2bf(v.x);
        wt[c4*4 + 1][k] = f2bf(v.y);
        wt[c4*4 + 2][k] = f2bf(v.z);
        wt[c4*4 + 3][k] = f2bf(v.w);
    }

    // stage X chunk (128x64 fp32 -> bf16)
    #pragma unroll
    for (int it = 0; it < 8; it++) {
        int i = t + it * 256;
        int row = i >> 4, c4 = i & 15;
        float4 v = *(const float4*)(x + (size_t)(r0 + row) * DIM + s*64 + c4*4);
        ushort4 u;
        u.x = f2bf(v.x); u.y = f2bf(v.y); u.z = f2bf(v.z); u.w = f2bf(v.w);
        *(ushort4*)&xs[row][c4*4] = u;
    }
    __syncthreads();

    f32x4 acc[2][4];
    #pragma unroll
    for (int rt = 0; rt < 2; rt++)
        #pragma unroll
        for (int ct = 0; ct < 4; ct++)
            acc[rt][ct] = (f32x4){0.f, 0.f, 0.f, 0.f};

    bf16x8 af[2][2], bfr[4][2];
    #pragma unroll
    for (int rt = 0; rt < 2; rt++)
        #pragma unroll
        for (int kk = 0; kk < 2; kk++)
            af[rt][kk] = *(const bf16x8*)&xs[wave*32 + rt*16 + l16][kk*32 + quad*8];
    #pragma unroll
    for (int ct = 0; ct < 4; ct++)
        #pragma unroll
        for (int kk = 0; kk < 2; kk++)
            bfr[ct][kk] = *(const bf16x8*)&wt[ct*16 + l16][kk*32 + quad*8];

    #pragma unroll
    for (int kk = 0; kk < 2; kk++)
        #pragma unroll
        for (int rt = 0; rt < 2; rt++)
            #pragma unroll
            for (int ct = 0; ct < 4; ct++)
                acc[rt][ct] = __builtin_amdgcn_mfma_f32_16x16x32_bf16(
                    af[rt][kk], bfr[ct][kk], acc[rt][ct], 0, 0, 0);

    // store pre-BN fp32 y to its final location (baseline-proven pattern:
    // 16 consecutive lanes cover one 64B segment per row)
    #pragma unroll
    for (int rt = 0; rt < 2; rt++)
        #pragma unroll
        for (int ct = 0; ct < 4; ct++) {
            int col = ct*16 + l16;
            #pragma unroll
            for (int r = 0; r < 4; r++) {
                int row = r0 + wave*32 + rt*16 + quad*4 + r;
                out[(size_t)row * DIM + s*64 + col] = acc[rt][ct][r];
            }
        }

    // per-thread column partials -> wave shuffle -> cross-wave LDS -> part
    float s1[4], s2[4];
    #pragma unroll
    for (int ct = 0; ct < 4; ct++) { s1[ct] = 0.f; s2[ct] = 0.f; }
    #pragma unroll
    for (int rt = 0; rt < 2; rt++)
        #pragma unroll
        for (int ct = 0; ct < 4; ct++)
            #pragma unroll
            for (int r = 0; r < 4; r++) {
                float v = acc[rt][ct][r];
                s1[ct] += v; s2[ct] += v * v;
            }
    #pragma unroll
    for (int ct = 0; ct < 4; ct++) {
        float a = s1[ct], b = s2[ct];
        a += __shfl_xor(a, 16); b += __shfl_xor(b, 16);
        a += __shfl_xor(a, 32); b += __shfl_xor(b, 32);
        if (quad == 0) {
            red1[wave][ct*16 + l16] = a;
            red2[wave][ct*16 + l16] = b;
        }
    }
    __syncthreads();
    if (t < 64) {
        float a = red1[0][t] + red1[1][t] + red1[2][t] + red1[3][t];
        float b = red2[0][t] + red2[1][t] + red2[2][t] + red2[3][t];
        size_t base = (size_t)(s * NCHUNK + blockIdx.x) * 128;
        part[base + t]      = a;
        part[base + 64 + t] = b;
    }
}

// K2: streaming in-place epilogue. Finalize stats (redundant per block,
// L2-hot), then out <- relu(out*sc + sh), float4 read-modify-write.
// Each address is owned by exactly one thread; K1 finished first (stream
// order) -> no race. out was just written, so reads are mostly L3 hits.
__global__ __launch_bounds__(256) void bn_apply(
    const float* __restrict__ part, const float* __restrict__ gamma,
    const float* __restrict__ beta, float* __restrict__ out)
{
    __shared__ float scol[64], shcol[64];

    const int s  = blockIdx.y;
    const int r0 = blockIdx.x * ROWS_PB;
    const int t  = threadIdx.x;

    if (t < 64) {
        float a = 0.f, b = 0.f;
        #pragma unroll 8
        for (int p = 0; p < NCHUNK; p++) {
            size_t base = (size_t)(s * NCHUNK + p) * 128;
            a += part[base + t];
            b += part[base + 64 + t];
        }
        float mean = a * (1.f / BATCH);
        float var  = b * (1.f / BATCH) - mean * mean;
        float rstd = rsqrtf(var + BN_EPS);
        float sc = gamma[s*64 + t] * rstd;
        scol[t]  = sc;
        shcol[t] = beta[s*64 + t] - mean * sc;
    }
    __syncthreads();

    // 128 rows x 64 cols = 2048 float4s; 8 per thread, 16B/lane both ways
    #pragma unroll
    for (int it = 0; it < 8; it++) {
        int i = t + it * 256;
        int row = i >> 4, c4 = i & 15;
        float* p = out + (size_t)(r0 + row) * DIM + s*64 + c4*4;
        float4 v = *(const float4*)p;
        int c0 = c4*4;
        v.x = fmaxf(fmaf(v.x, scol[c0+0], shcol[c0+0]), 0.f);
        v.y = fmaxf(fmaf(v.y, scol[c0+1], shcol[c0+1]), 0.f);
        v.z = fmaxf(fmaf(v.z, scol[c0+2], shcol[c0+2]), 0.f);
        v.w = fmaxf(fmaf(v.w, scol[c0+3], shcol[c0+3]), 0.f);
        *(float4*)p = v;
    }
}

extern "C" void kernel_launch(void* const* d_in, const int* in_sizes, int n_in,
                              void* d_out, int out_size, void* d_ws, size_t ws_size,
                              hipStream_t stream) {
    const float* x     = (const float*)d_in[0];
    const float* w     = (const float*)d_in[1];
    // d_in[2] = bias: cancels exactly in BatchNorm (mean subtraction) — unused
    const float* gamma = (const float*)d_in[3];
    const float* beta  = (const float*)d_in[4];
    float* out  = (float*)d_out;
    float* part = (float*)d_ws;    // 1 MiB — the baseline-validated footprint

    gemm_stats<<<dim3(NCHUNK, NSPLIT), 256, 0, stream>>>(x, w, part, out);
    bn_apply<<<dim3(NCHUNK, NSPLIT), 256, 0, stream>>>(part, gamma, beta, out);
}

// Round 4
// 176.966 us; speedup vs baseline: 1.0504x; 1.0467x over previous
//
#include <hip/hip_runtime.h>

#define BATCH 4096
#define DIM 4096
#define NSPLIT 64
#define ROWS_PB 128
#define NCHUNK 32            // BATCH / ROWS_PB
#define BN_EPS 1e-3f

typedef __attribute__((ext_vector_type(8))) short bf16x8;
typedef __attribute__((ext_vector_type(8))) unsigned short ushort8;
typedef __attribute__((ext_vector_type(4))) float f32x4;

__device__ inline unsigned short f2bf(float f) {
    union { float f; unsigned int u; } c; c.f = f;
    unsigned int u = c.u;
    u += 0x7FFFu + ((u >> 16) & 1u);   // round-to-nearest-even
    return (unsigned short)(u >> 16);
}

__device__ inline float bf2f(unsigned short h) {
    union { unsigned int u; float f; } c;
    c.u = (unsigned int)h << 16;
    return c.f;
}

// K1: GEMM once, latency-lean.
//  - A-fragments loaded DIRECTLY global->reg (8 independent float4 loads/lane;
//    no X LDS staging, no barrier on the X path).
//  - W block staged via LDS (transposed) — only 9.2 KB; total LDS 11.5 KB.
//  - Emits per-block column sum/sumsq partials into part (1 MiB validated ws)
//    and y as bf16 packed into the block's OWN out-tile (rows r0..r0+63 of its
//    128x64 region => 64 rows x 16 ushort8 units), 16B/lane coalesced.
//  - Bias dropped: cancels exactly under BatchNorm mean subtraction.
__global__ __launch_bounds__(256) void gemm_stats(
    const float* __restrict__ x, const float* __restrict__ w,
    float* __restrict__ part, float* __restrict__ out)
{
    __shared__ unsigned short wt[64][72];
    __shared__ float red1[4][64], red2[4][64];

    const int s  = blockIdx.y;
    const int r0 = blockIdx.x * ROWS_PB;
    const int t  = threadIdx.x;
    const int lane = t & 63, wave = t >> 6;
    const int quad = lane >> 4, l16 = lane & 15;

    // stage W_s transposed (fp32 -> bf16), coalesced float4 reads
    for (int i = t; i < 1024; i += 256) {
        int k = i >> 4, c4 = i & 15;
        float4 v = *(const float4*)(w + (size_t)(s*64 + k) * DIM + s*64 + c4*4);
        wt[c4*4 + 0][k] = f2bf(v.x);
        wt[c4*4 + 1][k] = f2bf(v.y);
        wt[c4*4 + 2][k] = f2bf(v.z);
        wt[c4*4 + 3][k] = f2bf(v.w);
    }

    // A-fragments: direct global->reg, 8 independent 16B loads (full MLP)
    float4 xv[2][2][2];
    #pragma unroll
    for (int rt = 0; rt < 2; rt++)
        #pragma unroll
        for (int kk = 0; kk < 2; kk++)
            #pragma unroll
            for (int h = 0; h < 2; h++)
                xv[rt][kk][h] = *(const float4*)(
                    x + (size_t)(r0 + wave*32 + rt*16 + l16) * DIM
                      + s*64 + kk*32 + quad*8 + h*4);

    __syncthreads();   // wt ready

    bf16x8 af[2][2], bfr[4][2];
    #pragma unroll
    for (int rt = 0; rt < 2; rt++)
        #pragma unroll
        for (int kk = 0; kk < 2; kk++) {
            bf16x8 a;
            a[0] = (short)f2bf(xv[rt][kk][0].x);
            a[1] = (short)f2bf(xv[rt][kk][0].y);
            a[2] = (short)f2bf(xv[rt][kk][0].z);
            a[3] = (short)f2bf(xv[rt][kk][0].w);
            a[4] = (short)f2bf(xv[rt][kk][1].x);
            a[5] = (short)f2bf(xv[rt][kk][1].y);
            a[6] = (short)f2bf(xv[rt][kk][1].z);
            a[7] = (short)f2bf(xv[rt][kk][1].w);
            af[rt][kk] = a;
        }
    #pragma unroll
    for (int ct = 0; ct < 4; ct++)
        #pragma unroll
        for (int kk = 0; kk < 2; kk++)
            bfr[ct][kk] = *(const bf16x8*)&wt[ct*16 + l16][kk*32 + quad*8];

    f32x4 acc[2][4];
    #pragma unroll
    for (int rt = 0; rt < 2; rt++)
        #pragma unroll
        for (int ct = 0; ct < 4; ct++)
            acc[rt][ct] = (f32x4){0.f, 0.f, 0.f, 0.f};

    #pragma unroll
    for (int kk = 0; kk < 2; kk++)
        #pragma unroll
        for (int rt = 0; rt < 2; rt++)
            #pragma unroll
            for (int ct = 0; ct < 4; ct++)
                acc[rt][ct] = __builtin_amdgcn_mfma_f32_16x16x32_bf16(
                    af[rt][kk], bfr[ct][kk], acc[rt][ct], 0, 0, 0);

    // pack y -> bf16 into the block's own out-tile scratch (no race: this
    // exact region is read back only by K2's block (s, blockIdx.x))
    #pragma unroll
    for (int j = 0; j < 4; j++) {
        const int f0 = 2*j, f1 = 2*j + 1;
        const f32x4 a0 = acc[f0 >> 2][f0 & 3];
        const f32x4 a1 = acc[f1 >> 2][f1 & 3];
        ushort8 pk;
        pk[0] = f2bf(a0[0]); pk[1] = f2bf(a0[1]);
        pk[2] = f2bf(a0[2]); pk[3] = f2bf(a0[3]);
        pk[4] = f2bf(a1[0]); pk[5] = f2bf(a1[1]);
        pk[6] = f2bf(a1[2]); pk[7] = f2bf(a1[3]);
        int u = j*256 + t;   // 1024 ushort8 units = 64 rows x 16 units
        unsigned short* dst =
            (unsigned short*)(out + (size_t)(r0 + (u >> 4)) * DIM + s*64)
            + (u & 15) * 8;
        *(ushort8*)dst = pk;
    }

    // per-thread column partials -> wave shuffle -> cross-wave LDS -> part
    float s1[4], s2[4];
    #pragma unroll
    for (int ct = 0; ct < 4; ct++) { s1[ct] = 0.f; s2[ct] = 0.f; }
    #pragma unroll
    for (int rt = 0; rt < 2; rt++)
        #pragma unroll
        for (int ct = 0; ct < 4; ct++)
            #pragma unroll
            for (int r = 0; r < 4; r++) {
                float v = acc[rt][ct][r];
                s1[ct] += v; s2[ct] += v * v;
            }
    #pragma unroll
    for (int ct = 0; ct < 4; ct++) {
        float a = s1[ct], b = s2[ct];
        a += __shfl_xor(a, 16); b += __shfl_xor(b, 16);
        a += __shfl_xor(a, 32); b += __shfl_xor(b, 32);
        if (quad == 0) {
            red1[wave][ct*16 + l16] = a;
            red2[wave][ct*16 + l16] = b;
        }
    }
    __syncthreads();
    if (t < 64) {
        float a = red1[0][t] + red1[1][t] + red1[2][t] + red1[3][t];
        float b = red2[0][t] + red2[1][t] + red2[2][t] + red2[3][t];
        size_t base = (size_t)(s * NCHUNK + blockIdx.x) * 128;
        part[base + t]      = a;
        part[base + 64 + t] = b;
    }
}

// K2: finalize stats (parallel reduce over all 256 threads), read back the
// block's own bf16 y tile, BN + ReLU, fp32 scatter store. Explicit
// vmcnt(0)+barrier orders tile-read before any tile-overwrite.
__global__ __launch_bounds__(256) void bn_apply(
    const float* __restrict__ part, const float* __restrict__ gamma,
    const float* __restrict__ beta, float* __restrict__ out)
{
    __shared__ float redA[4][64], redB[4][64];
    __shared__ float scol[64], shcol[64];

    const int s  = blockIdx.y;
    const int r0 = blockIdx.x * ROWS_PB;
    const int t  = threadIdx.x;
    const int lane = t & 63, wave = t >> 6;
    const int quad = lane >> 4, l16 = lane & 15;

    // load own y tile early (issue all 4 loads before the reduce)
    ushort8 yv[4];
    #pragma unroll
    for (int j = 0; j < 4; j++) {
        int u = j*256 + t;
        const unsigned short* src =
            (const unsigned short*)(out + (size_t)(r0 + (u >> 4)) * DIM + s*64)
            + (u & 15) * 8;
        yv[j] = *(const ushort8*)src;
    }

    // parallel part-reduce: group g (=wave) covers chunks g*8..g*8+7, col = lane
    {
        float a = 0.f, b = 0.f;
        #pragma unroll
        for (int p8 = 0; p8 < 8; p8++) {
            int p = wave*8 + p8;
            size_t base = (size_t)(s * NCHUNK + p) * 128;
            a += part[base + lane];
            b += part[base + 64 + lane];
        }
        redA[wave][lane] = a;
        redB[wave][lane] = b;
    }

    // all global loads (y + part) must have landed before any thread stores
    asm volatile("s_waitcnt vmcnt(0)" ::: "memory");
    __syncthreads();

    if (t < 64) {
        float a = redA[0][t] + redA[1][t] + redA[2][t] + redA[3][t];
        float b = redB[0][t] + redB[1][t] + redB[2][t] + redB[3][t];
        float mean = a * (1.f / BATCH);
        float var  = b * (1.f / BATCH) - mean * mean;
        float rstd = rsqrtf(var + BN_EPS);
        float sc = gamma[s*64 + t] * rstd;
        scol[t]  = sc;
        shcol[t] = beta[s*64 + t] - mean * sc;
    }
    __syncthreads();

    #pragma unroll
    for (int j = 0; j < 4; j++) {
        #pragma unroll
        for (int h = 0; h < 2; h++) {
            const int f  = 2*j + h;
            const int rt = f >> 2, ct = f & 3;
            const int col = ct*16 + l16;
            const float sc = scol[col], sh = shcol[col];
            #pragma unroll
            for (int r = 0; r < 4; r++) {
                float v = fmaxf(fmaf(bf2f((unsigned short)yv[j][h*4 + r]), sc, sh), 0.f);
                int row = r0 + wave*32 + rt*16 + quad*4 + r;
                out[(size_t)row * DIM + s*64 + col] = v;
            }
        }
    }
}

extern "C" void kernel_launch(void* const* d_in, const int* in_sizes, int n_in,
                              void* d_out, int out_size, void* d_ws, size_t ws_size,
                              hipStream_t stream) {
    const float* x     = (const float*)d_in[0];
    const float* w     = (const float*)d_in[1];
    // d_in[2] = bias: cancels exactly in BatchNorm (mean subtraction) — unused
    const float* gamma = (const float*)d_in[3];
    const float* beta  = (const float*)d_in[4];
    float* out  = (float*)d_out;
    float* part = (float*)d_ws;    // 1 MiB — the baseline-validated footprint

    gemm_stats<<<dim3(NCHUNK, NSPLIT), 256, 0, stream>>>(x, w, part, out);
    bn_apply<<<dim3(NCHUNK, NSPLIT), 256, 0, stream>>>(part, gamma, beta, out);
}